// Round 1
// 266.430 us; speedup vs baseline: 1.0263x; 1.0263x over previous
//
#include <hip/hip_runtime.h>
#include <hip/hip_bf16.h>

// MoE: N=16384 tokens, D=1024, E=8 experts, top-2 routing.
// R6: moe_gemm rewritten as 192x256 tile, BK=64, 8 waves, depth-2 counted-vmcnt
// pipeline (T3+T4), XOR chunk swizzle on both operands via pre-swizzled global
// source (T2, rule #21), setprio around MFMA clusters (T5). A and B both staged
// with global_load_lds width=16 into 112KB double-buffered LDS. wb is now plain
// row-major. Router/scan/scatter/combine unchanged from R5.

constexpr int DIMS = 1024;
constexpr int NE   = 8;
constexpr int ROUTER_BLOCKS = 1024;           // 16 tokens per block
constexpr int WCONV_BLOCKS  = NE * DIMS * DIMS / (8 * 256);  // 4096
constexpr int BM = 192, BN = 256, BK = 64;
constexpr int RT_PER_XCD = 23;   // 23*8=184 >= worst-case sum ceil(cnt/192)=178

typedef __attribute__((ext_vector_type(8))) short short8;
typedef __attribute__((ext_vector_type(4))) short short4_t;
typedef __attribute__((ext_vector_type(4))) float f32x4;

typedef const __attribute__((address_space(1))) void* gp_t;
typedef __attribute__((address_space(3))) void* sp_t;

__device__ __forceinline__ float b2f(unsigned short u) {
  union { unsigned int i; float f; } x; x.i = ((unsigned)u) << 16; return x.f;
}
__device__ __forceinline__ short f2bs(float f) {
  __hip_bfloat16 h = __float2bfloat16(f);
  return *(short*)&h;
}

// ---------------- prep: router blocks [0,1024) + wconv blocks [1024,5120) ----
// wconv now writes wb ROW-MAJOR [e][o][d] bf16 (fully coalesced streaming cvt).
// router: NO global atomics — writes per-block counts + per-slot meta.
__global__ __launch_bounds__(256) void prep_kernel(
    const float* __restrict__ x, const float* __restrict__ rw,
    const float* __restrict__ rb, const float* __restrict__ ew,
    __hip_bfloat16* __restrict__ xb, __hip_bfloat16* __restrict__ wb,
    int* __restrict__ blk_cnt, int* __restrict__ tmp_meta,
    float* __restrict__ tmp_gate, int n_tok) {
  const int tid = threadIdx.x;

  if ((int)blockIdx.x >= ROUTER_BLOCKS) {
    unsigned g = (unsigned)(blockIdx.x - ROUTER_BLOCKS) * 256 + tid;  // 8-elem chunk
    const float4* src = (const float4*)(ew + (size_t)g * 8);
    float4 a = src[0], b = src[1];
    union { __hip_bfloat16 h[8]; float4 f; } u;
    u.h[0] = __float2bfloat16(a.x); u.h[1] = __float2bfloat16(a.y);
    u.h[2] = __float2bfloat16(a.z); u.h[3] = __float2bfloat16(a.w);
    u.h[4] = __float2bfloat16(b.x); u.h[5] = __float2bfloat16(b.y);
    u.h[6] = __float2bfloat16(b.z); u.h[7] = __float2bfloat16(b.w);
    ((float4*)wb)[g] = u.f;
    return;
  }

  // ---- router role: 16 tokens/block, wave-per-token, float4 vectorized ----
  __shared__ float s_rw[NE * DIMS];   // 32 KB
  __shared__ int s_cnt[NE];
  __shared__ int s_e[32];
  __shared__ float s_g[32];
  __shared__ int s_pos[32];

  const float4* rw4g = (const float4*)rw;
  float4* s4 = (float4*)s_rw;
  for (int i = tid; i < NE * DIMS / 4; i += 256) s4[i] = rw4g[i];
  if (tid < NE) s_cnt[tid] = 0;
  __syncthreads();

  const float4* s_rw4 = (const float4*)s_rw;
  const int wave = tid >> 6, lane = tid & 63;
  for (int i = 0; i < 4; ++i) {
    int t = blockIdx.x * 16 + wave * 4 + i;
    const float4* xr = (const float4*)(x + (size_t)t * DIMS);
    short4_t* xw = (short4_t*)(xb + (size_t)t * DIMS);
    float a[NE];
#pragma unroll
    for (int e = 0; e < NE; ++e) a[e] = 0.f;
#pragma unroll
    for (int j = 0; j < 4; ++j) {
      float4 v = xr[lane + j * 64];
      short4_t p;
      p[0] = f2bs(v.x); p[1] = f2bs(v.y); p[2] = f2bs(v.z); p[3] = f2bs(v.w);
      xw[lane + j * 64] = p;
#pragma unroll
      for (int e = 0; e < NE; ++e) {
        float4 w = s_rw4[e * 256 + lane + j * 64];
        a[e] = fmaf(v.x, w.x, fmaf(v.y, w.y, fmaf(v.z, w.z, fmaf(v.w, w.w, a[e]))));
      }
    }
#pragma unroll
    for (int off = 32; off > 0; off >>= 1) {
#pragma unroll
      for (int e = 0; e < NE; ++e) a[e] += __shfl_xor(a[e], off, 64);
    }
    if (lane == 0) {
      float l[NE];
#pragma unroll
      for (int e = 0; e < NE; ++e) l[e] = a[e] + rb[e];
      int e0 = 0;
#pragma unroll
      for (int e = 1; e < NE; ++e) if (l[e] > l[e0]) e0 = e;
      int e1 = (e0 == 0) ? 1 : 0;
#pragma unroll
      for (int e = 0; e < NE; ++e) if (e != e0 && l[e] > l[e1]) e1 = e;
      float r = expf(l[e1] - l[e0]);   // <= 1
      float g0 = 1.f / (1.f + r);
      float g1 = 1.f - g0;
      int ai = (wave * 4 + i) * 2;
      int p0 = atomicAdd(&s_cnt[e0], 1);   // LDS atomic only
      int p1 = atomicAdd(&s_cnt[e1], 1);
      s_e[ai] = e0; s_g[ai] = g0; s_pos[ai] = p0;
      s_e[ai + 1] = e1; s_g[ai + 1] = g1; s_pos[ai + 1] = p1;
    }
  }
  __syncthreads();
  if (tid < NE) blk_cnt[blockIdx.x * NE + tid] = s_cnt[tid];
  if (tid < 32) {
    int s = blockIdx.x * 32 + tid;
    tmp_meta[s] = s_e[tid] | (s_pos[tid] << 3);
    tmp_gate[s] = s_g[tid];
  }
}

// ---------------- scan: exclusive prefix of blk_cnt per expert ----------------
__global__ __launch_bounds__(512) void scan_kernel(
    const int* __restrict__ blk_cnt, int* __restrict__ blk_base,
    int* __restrict__ counts) {
  const int e = threadIdx.x >> 6, lane = threadIdx.x & 63;
  int running = 0;
  for (int c = 0; c < ROUTER_BLOCKS / 64; ++c) {
    int v = blk_cnt[(c * 64 + lane) * NE + e];
    int incl = v;
#pragma unroll
    for (int off = 1; off < 64; off <<= 1) {
      int t = __shfl_up(incl, off, 64);
      if (lane >= off) incl += t;
    }
    blk_base[(c * 64 + lane) * NE + e] = running + incl - v;
    running += __shfl(incl, 63, 64);
  }
  if (lane == 0) counts[e] = running;
}

// ---------------- scatter: place entries/gates ----------------
__global__ __launch_bounds__(256) void scatter_kernel(
    const int* __restrict__ tmp_meta, const float* __restrict__ tmp_gate,
    const int* __restrict__ blk_base, int* __restrict__ entries,
    float* __restrict__ gates, int n_tok) {
  int s = blockIdx.x * 256 + threadIdx.x;       // slot in [0, 2*n_tok)
  int meta = tmp_meta[s];
  int e = meta & 7, pos = meta >> 3;
  int p = blk_base[(s >> 5) * NE + e] + pos;
  entries[e * n_tok + p] = ((s >> 1) << 1) | (s & 1);   // token*2 + slot parity
  gates[e * n_tok + p] = tmp_gate[s];
}

// ---------------- grouped gathered GEMM ----------------
// 192x256 tile, BK=64; 8 waves (2x4) of 96x64 = 6x4 of 16x16x32 bf16.
// LDS: As[2][192*64] (24KB ea) + Bs[2][256*64] (32KB ea) = 112KB -> 1 block/CU.
// Swizzle: logical chunk q of row R stored at physical chunk q^(R&7) (row =
// 128B = 8 x 16B chunks). gload_lds dest is linear; the source address carries
// the inverse permutation (qsw = (l&7)^(l>>3)); ds_read applies the same XOR.
// Pipeline: depth-2 prefetch, counted s_waitcnt vmcnt(7) (7 loads/thread/tile),
// never drained to 0 in the main loop. Each s_barrier is preceded by an asm
// volatile waitcnt w/ memory clobber => compiler cannot move LDS ops across.
__global__ __launch_bounds__(512, 2) void moe_gemm(
    const __hip_bfloat16* __restrict__ xb, const __hip_bfloat16* __restrict__ wb,
    const float* __restrict__ eb, const int* __restrict__ counts,
    const int* __restrict__ entries, const float* __restrict__ gates,
    __hip_bfloat16* __restrict__ y, int n_tok) {
  const int xcd = blockIdx.x & 7;
  const int j = blockIdx.x >> 3;                  // [0, 92)
  const int ct = j & 3;
  const int virt = xcd * RT_PER_XCD + (j >> 2);   // virtual row-tile id

  int e = -1, rt = 0, cnt = 0, acc_t = 0;
#pragma unroll
  for (int i = 0; i < NE; ++i) {
    int c = counts[i];
    int t = (c + BM - 1) / BM;
    if (e < 0 && virt < acc_t + t) { e = i; rt = virt - acc_t; cnt = c; }
    acc_t += t;
  }
  if (e < 0) return;

  __shared__ __align__(16) char smem[2 * 24576 + 2 * 32768];  // 112 KB

  const int tid = threadIdx.x;
  const int l = tid & 63, w = tid >> 6;
  const int row0 = rt * BM;
  const int n0 = ct * BN;

  // ---- staging source pointers (pre-swizzled chunk within 8-chunk row) ----
  const int qsw = (l & 7) ^ (l >> 3);
  const __hip_bfloat16* aptr[3];
  const __hip_bfloat16* bptr[4];
#pragma unroll
  for (int i = 0; i < 3; ++i) {
    int R = (i * 8 + w) * 8 + (l >> 3);           // [0,192)
    int gr = row0 + R;
    int ent = (gr < cnt) ? entries[e * n_tok + gr] : 0;
    aptr[i] = xb + (size_t)(ent >> 1) * DIMS + qsw * 8;
  }
#pragma unroll
  for (int i = 0; i < 4; ++i) {
    int R = (i * 8 + w) * 8 + (l >> 3);           // [0,256)
    bptr[i] = wb + ((size_t)e << 20) + (size_t)(n0 + R) * DIMS + qsw * 8;
  }

  // ---- fragment read offsets (bytes within a buffer) ----
  const int fr = l & 15, quad = l >> 4;
  const int wr = w >> 2, wc = w & 3;              // 2 x 4 wave grid
  const int swz = (quad ^ (fr & 7)) << 4;         // (R&7)==(fr&7): bases %8==0
  const int aoff0 = (wr * 96 + fr) * 128 + swz;   // + mt*2048; ks=1: ^64
  const int boff0 = (wc * 64 + fr) * 128 + swz;   // + nt*2048; ks=1: ^64

  auto stage = [&](int buf, int kt) {
    const int koff = kt * 64;
#pragma unroll
    for (int i = 0; i < 3; ++i)
      __builtin_amdgcn_global_load_lds(
          (gp_t)(aptr[i] + koff),
          (sp_t)(smem + buf * 24576 + (i * 8 + w) * 1024 + l * 16), 16, 0, 0);
#pragma unroll
    for (int i = 0; i < 4; ++i)
      __builtin_amdgcn_global_load_lds(
          (gp_t)(bptr[i] + koff),
          (sp_t)(smem + 49152 + buf * 32768 + (i * 8 + w) * 1024 + l * 16), 16, 0, 0);
  };

  f32x4 acc[6][4] = {};

  // prologue: tiles 0 and 1 in flight (14 loads), wait oldest 7 (tile 0)
  stage(0, 0);
  stage(1, 1);
  asm volatile("s_waitcnt vmcnt(7)" ::: "memory");
  __builtin_amdgcn_s_barrier();

  auto body = [&](int kt, int mode) {   // mode: 0=steady, 1=kt==14, 2=last
    const int cur = kt & 1;
    const char* As = smem + cur * 24576;
    const char* Bs = smem + 49152 + cur * 32768;
    // ---- phase 1: ks=0 frags + MFMA ----
    short8 af[6], bf[4];
#pragma unroll
    for (int mt = 0; mt < 6; ++mt) af[mt] = *(const short8*)(As + aoff0 + mt * 2048);
#pragma unroll
    for (int nt = 0; nt < 4; ++nt) bf[nt] = *(const short8*)(Bs + boff0 + nt * 2048);
    __builtin_amdgcn_s_setprio(1);
#pragma unroll
    for (int mt = 0; mt < 6; ++mt)
#pragma unroll
      for (int nt = 0; nt < 4; ++nt)
        acc[mt][nt] = __builtin_amdgcn_mfma_f32_16x16x32_bf16(af[mt], bf[nt], acc[mt][nt], 0, 0, 0);
    __builtin_amdgcn_s_setprio(0);
    // ---- phase 2: ks=1 frags, then free buf[cur] and restage it ----
    short8 af2[6], bf2[4];
#pragma unroll
    for (int mt = 0; mt < 6; ++mt) af2[mt] = *(const short8*)(As + ((aoff0 + mt * 2048) ^ 64));
#pragma unroll
    for (int nt = 0; nt < 4; ++nt) bf2[nt] = *(const short8*)(Bs + ((boff0 + nt * 2048) ^ 64));
    asm volatile("s_waitcnt lgkmcnt(0)" ::: "memory");   // my reads landed
    __builtin_amdgcn_s_barrier();                        // all waves done w/ buf[cur]
    if (mode == 0) stage(cur, kt + 2);                   // tile t+2 -> buf[cur]
    __builtin_amdgcn_s_setprio(1);
#pragma unroll
    for (int mt = 0; mt < 6; ++mt)
#pragma unroll
      for (int nt = 0; nt < 4; ++nt)
        acc[mt][nt] = __builtin_amdgcn_mfma_f32_16x16x32_bf16(af2[mt], bf2[nt], acc[mt][nt], 0, 0, 0);
    __builtin_amdgcn_s_setprio(0);
    if (mode == 0) {
      asm volatile("s_waitcnt vmcnt(7)" ::: "memory");   // tile t+1 complete
      __builtin_amdgcn_s_barrier();
    } else if (mode == 1) {
      asm volatile("s_waitcnt vmcnt(0)" ::: "memory");   // drain tile 15
      __builtin_amdgcn_s_barrier();
    }
  };

#pragma unroll 1
  for (int kt = 0; kt < 14; ++kt) body(kt, 0);
  body(14, 1);
  body(15, 2);

  // ---- epilogue: C/D layout col=lane&15, row=(lane>>4)*4+reg ----
  float bias[4];
#pragma unroll
  for (int nt = 0; nt < 4; ++nt) bias[nt] = eb[e * DIMS + n0 + wc * 64 + nt * 16 + fr];
#pragma unroll
  for (int mt = 0; mt < 6; ++mt) {
#pragma unroll
    for (int r = 0; r < 4; ++r) {
      int m = wr * 96 + mt * 16 + quad * 4 + r;
      int gr = row0 + m;
      if (gr < cnt) {
        int ent = entries[e * n_tok + gr];
        float g = gates[e * n_tok + gr];
        __hip_bfloat16* yp = y + (size_t)ent * DIMS + n0 + wc * 64 + fr;
#pragma unroll
        for (int nt = 0; nt < 4; ++nt)
          yp[nt * 16] = __float2bfloat16(g * (acc[mt][nt][r] + bias[nt]));
      }
    }
  }
}

// ---------------- combine: out[n] = y[n,0] + y[n,1] ----------------
__global__ __launch_bounds__(256) void combine_kernel(const __hip_bfloat16* __restrict__ y,
                                                      float* __restrict__ out) {
  size_t idx = (size_t)blockIdx.x * 256 + threadIdx.x;  // one 8-wide chunk
  size_t n = idx >> 7;
  int c = (int)(idx & 127) << 3;
  short8 v0 = *(const short8*)(y + (n * 2) * DIMS + c);
  short8 v1 = *(const short8*)(y + (n * 2 + 1) * DIMS + c);
  float4 o0, o1;
  o0.x = b2f((unsigned short)v0[0]) + b2f((unsigned short)v1[0]);
  o0.y = b2f((unsigned short)v0[1]) + b2f((unsigned short)v1[1]);
  o0.z = b2f((unsigned short)v0[2]) + b2f((unsigned short)v1[2]);
  o0.w = b2f((unsigned short)v0[3]) + b2f((unsigned short)v1[3]);
  o1.x = b2f((unsigned short)v0[4]) + b2f((unsigned short)v1[4]);
  o1.y = b2f((unsigned short)v0[5]) + b2f((unsigned short)v1[5]);
  o1.z = b2f((unsigned short)v0[6]) + b2f((unsigned short)v1[6]);
  o1.w = b2f((unsigned short)v0[7]) + b2f((unsigned short)v1[7]);
  float* op = out + n * DIMS + c;
  ((float4*)op)[0] = o0;
  ((float4*)op)[1] = o1;
}

extern "C" void kernel_launch(void* const* d_in, const int* in_sizes, int n_in,
                              void* d_out, int out_size, void* d_ws, size_t ws_size,
                              hipStream_t stream) {
  const float* x  = (const float*)d_in[0];
  const float* rw = (const float*)d_in[1];
  const float* rb = (const float*)d_in[2];
  const float* ew = (const float*)d_in[3];
  const float* eb = (const float*)d_in[4];
  float* out = (float*)d_out;
  const int n_tok = in_sizes[0] / DIMS;  // 16384
  const int n_slot = 2 * n_tok;

  // workspace layout
  char* ws = (char*)d_ws;
  size_t off = 0;
  int* counts = (int*)ws;                      off += 256;
  int* blk_cnt = (int*)(ws + off);             off += (size_t)ROUTER_BLOCKS * NE * 4;
  int* blk_base = (int*)(ws + off);            off += (size_t)ROUTER_BLOCKS * NE * 4;
  int* tmp_meta = (int*)(ws + off);            off += (size_t)n_slot * 4;
  float* tmp_gate = (float*)(ws + off);        off += (size_t)n_slot * 4;
  __hip_bfloat16* xb = (__hip_bfloat16*)(ws + off); off += (size_t)n_tok * DIMS * 2;
  __hip_bfloat16* wb = (__hip_bfloat16*)(ws + off); off += (size_t)NE * DIMS * DIMS * 2;
  int*   entries = (int*)(ws + off);           off += (size_t)NE * n_tok * 4;
  float* gates   = (float*)(ws + off);         off += (size_t)NE * n_tok * 4;
  __hip_bfloat16* y = (__hip_bfloat16*)(ws + off); off += (size_t)n_slot * DIMS * 2;
  if (ws_size < off) return;  // signature: output stays exactly zero

  prep_kernel<<<ROUTER_BLOCKS + WCONV_BLOCKS, 256, 0, stream>>>(
      x, rw, rb, ew, xb, wb, blk_cnt, tmp_meta, tmp_gate, n_tok);
  scan_kernel<<<1, 512, 0, stream>>>(blk_cnt, blk_base, counts);
  scatter_kernel<<<n_slot / 256, 256, 0, stream>>>(
      tmp_meta, tmp_gate, blk_base, entries, gates, n_tok);
  moe_gemm<<<8 * RT_PER_XCD * 4, 512, 0, stream>>>(
      xb, wb, eb, counts, entries, gates, y, n_tok);
  combine_kernel<<<(unsigned)((size_t)n_tok * DIMS / 8 / 256), 256, 0, stream>>>(y, out);
}